// Round 17
// baseline (3197.160 us; speedup 1.0000x reference)
//
#include <hip/hip_runtime.h>
#include <math.h>
#include <stdint.h>

typedef unsigned long long u64;
typedef unsigned int u32;

#define CAP 4096
#define NTOT 261888  // 196608+49152+12288+3072+768

__device__ __forceinline__ u32 fkey32(float f) {
    u32 u = __float_as_uint(f);
    return (u & 0x80000000u) ? ~u : (u | 0x80000000u);
}

// ------- weight transpose -> f64 triplets, 32B padded:
// wT4[((ci*3+dy)*256 + oc)*4 + k] = w[oc][ci][dy*3+k], k=0..2 (k=3 pad)
__global__ __launch_bounds__(256) void k_transpose_w(const float* __restrict__ w,
                                                     double* __restrict__ wT4) {
    int t = blockIdx.x * 256 + threadIdx.x;
    if (t >= 768 * 256) return;
    int r = t >> 8;     // ci*3+dy
    int oc = t & 255;
    double* dst = &wT4[(size_t)t * 4];
    const float* src = &w[(size_t)oc * 2304 + r * 3];
    dst[0] = (double)src[0];
    dst[1] = (double)src[1];
    dst[2] = (double)src[2];
    dst[3] = 0.0;
}

// ======== L1: fused all-level conv3x3(f64 acc)+relu+heads, 4 blocks/CU ======
// f64 (w,x) fma chain VERBATIM r16 (bit-exact verified). Loads widened
// (b128), weight triplets contiguous, heads in 4 p-quarter passes, hout f32
// (it only ever fed (float) casts).
struct CArgs {
    const float* x[5];
    float* scores[5];
    float* deltas[5];
    const double* wT4;
    const float* cb;
    const float* clsw;
    const float* clsb;
    const float* bbw;
    const float* bbb;
};

__global__ __launch_bounds__(256, 4) void k_conv_heads(CArgs ca) {
    __shared__ __align__(16) double xs[64][3][20];  // 30720 B
    __shared__ double hsh[256][4];                  // 8192 B (p-quarter)
    __shared__ float hout[18][16];                  // 1152 B => 40064 B

    int b = blockIdx.x;
    int l, rel;
    if (b < 4096) { l = 0; rel = b; }
    else if (b < 5120) { l = 1; rel = b - 4096; }
    else if (b < 5376) { l = 2; rel = b - 5120; }
    else if (b < 5440) { l = 3; rel = b - 5376; }
    else { l = 4; rel = b - 5440; }
    const int HWs[5] = {256, 128, 64, 32, 16};
    int H = HWs[l], W = H;
    const float* __restrict__ x = ca.x[l];
    float* __restrict__ scores = ca.scores[l];
    float* __restrict__ deltas = ca.deltas[l];
    const double* __restrict__ wT4 = ca.wT4;

    int tid = threadIdx.x;
    int pos0 = rel * 16;
    int row = pos0 / W;
    int col0 = pos0 % W;

    double acc[16];
#pragma unroll
    for (int p = 0; p < 16; ++p) acc[p] = 0.0;

    for (int cc = 0; cc < 4; ++cc) {
        __syncthreads();
        for (int t = tid; t < 64 * 3 * 20; t += 256) {
            int a = t / 60;
            int r = t % 60;
            int dy = r / 20;
            int dxx = r % 20;
            float v = 0.f;
            int gy = row - 1 + dy;
            int gx = col0 - 1 + dxx;
            if (dxx < 18 && gy >= 0 && gy < H && gx >= 0 && gx < W)
                v = x[((size_t)(cc * 64 + a) * H + gy) * W + gx];
            xs[a][dy][dxx] = (double)v;  // exact conversion, once
        }
        __syncthreads();
        int oc = tid;
        for (int a = 0; a < 64; ++a) {
#pragma unroll
            for (int dy = 0; dy < 3; ++dy) {
                double xr[18];
                const double2* xp = (const double2*)&xs[a][dy][0];
#pragma unroll
                for (int q = 0; q < 9; ++q) {
                    double2 v2 = xp[q];
                    xr[2 * q] = v2.x;
                    xr[2 * q + 1] = v2.y;
                }
                int ridx = (cc * 64 + a) * 3 + dy;
                const double* wrow = &wT4[((size_t)ridx * 256 + oc) * 4];
                double2 w01 = *(const double2*)wrow;
                double w0 = w01.x;
                double w1 = w01.y;
                double w2 = wrow[2];
#pragma unroll
                for (int p = 0; p < 16; ++p) {
                    acc[p] = fma(w0, xr[p], acc[p]);
                    acc[p] = fma(w1, xr[p + 1], acc[p]);
                    acc[p] = fma(w2, xr[p + 2], acc[p]);
                }
            }
        }
    }
    // ---- heads in four p-quarter passes (same arithmetic & ci order) ----
    double bias = (double)ca.cb[tid];
    for (int qh = 0; qh < 4; ++qh) {
        __syncthreads();
#pragma unroll
        for (int p = 0; p < 4; ++p) hsh[tid][p] = fmax(acc[qh * 4 + p] + bias, 0.0);
        __syncthreads();
        for (int t = tid; t < 72; t += 256) {
            int p = t & 3, ch = t >> 2;
            double s = (ch < 6) ? (double)ca.clsb[ch] : (double)ca.bbb[ch - 6];
            const float* __restrict__ wv =
                (ch < 6) ? (ca.clsw + ch * 256) : (ca.bbw + (ch - 6) * 256);
            for (int ci = 0; ci < 256; ++ci) s += (double)wv[ci] * hsh[ci][p];
            hout[ch][qh * 4 + p] = (float)s;  // identical to (float) of r16's f64
        }
    }
    __syncthreads();
    for (int t = tid; t < 48; t += 256) {
        int p = t & 15, a = t >> 4;
        int posi = pos0 + p;
        float c0 = hout[a][p], c1 = hout[3 + a][p];
        float m = fmaxf(c0, c1);
        float e0 = expf(__fsub_rn(c0, m));
        float e1 = expf(__fsub_rn(c1, m));
        scores[(size_t)posi * 3 + a] = __fdiv_rn(e1, __fadd_rn(e0, e1));
    }
    for (int t = tid; t < 192; t += 256) {
        int p = t & 15, j = t >> 4;
        int posi = pos0 + p;
        int a = j >> 2, c = j & 3;
        deltas[((size_t)posi * 3 + a) * 4 + c] = hout[6 + j][p];
    }
}

// ============ top-K selection machinery (verbatim r16) ======================
struct SelArgs {
    const float* sc[5];
    u32* h12;
    u32* h24;
    u32* h8;
    u32* selst;
    u32* T32;
    u64* cand;
    u32* ccnt;
    int N[5], K[5];
    int needT[5];
};

__device__ __forceinline__ void lvl_lookup(int g, int& l, int& base) {
    if (g < 196608) { l = 0; base = 0; }
    else if (g < 245760) { l = 1; base = 196608; }
    else if (g < 258048) { l = 2; base = 245760; }
    else if (g < 261120) { l = 3; base = 258048; }
    else { l = 4; base = 261120; }
}

__device__ __forceinline__ void hblk_lookup(int b, int& l, int& base, int& n0) {
    if (b < 48) { l = 0; base = 0; n0 = b * 4096; }
    else if (b < 60) { l = 1; base = 196608; n0 = (b - 48) * 4096; }
    else { l = 2; base = 245760; n0 = (b - 60) * 4096; }
}

__global__ __launch_bounds__(256) void k_zero(SelArgs a) {
    int g = blockIdx.x * 256 + threadIdx.x;
    if (g < 5 * 4096) { a.h12[g] = 0; a.h24[g] = 0; }
    if (g < 5 * 256) a.h8[g] = 0;
    if (g < 5) a.ccnt[g] = 0;
}

__global__ __launch_bounds__(256) void k_h12(SelArgs a) {
    __shared__ u32 hist[4096];
    int l, base, n0;
    hblk_lookup(blockIdx.x, l, base, n0);
    int tid = threadIdx.x;
    for (int i = tid; i < 4096; i += 256) hist[i] = 0;
    __syncthreads();
    const float* sc = a.sc[l];
    int i0 = n0 + tid;
#pragma unroll
    for (int q = 0; q < 16; ++q) {
        u32 key = __float_as_uint(sc[i0 + q * 256]);
        atomicAdd(&hist[key >> 20], 1u);
    }
    __syncthreads();
    for (int i = tid; i < 4096; i += 256) {
        u32 c = hist[i];
        if (c) atomicAdd(&a.h12[l * 4096 + i], c);
    }
}

__global__ __launch_bounds__(1024) void k_sel12(SelArgs a) {
    __shared__ u32 h[4096];
    int l = blockIdx.x;
    if (!a.needT[l]) return;
    for (int i = threadIdx.x; i < 4096; i += 1024) h[i] = a.h12[l * 4096 + i];
    __syncthreads();
    if (threadIdx.x == 0) {
        u32 K = (u32)a.K[l], c = 0;
        for (int b = 4095; b >= 0; --b) {
            c += h[b];
            if (c >= K) {
                a.selst[l * 4 + 0] = (u32)b;
                a.selst[l * 4 + 1] = K - (c - h[b]);
                break;
            }
        }
    }
}

__global__ __launch_bounds__(256) void k_h24(SelArgs a) {
    __shared__ u32 hist[4096];
    int l, base, n0;
    hblk_lookup(blockIdx.x, l, base, n0);
    int tid = threadIdx.x;
    for (int i = tid; i < 4096; i += 256) hist[i] = 0;
    __syncthreads();
    const float* sc = a.sc[l];
    u32 topbin = a.selst[l * 4 + 0];
    int i0 = n0 + tid;
#pragma unroll
    for (int q = 0; q < 16; ++q) {
        u32 key = __float_as_uint(sc[i0 + q * 256]);
        if ((key >> 20) == topbin) atomicAdd(&hist[(key >> 8) & 0xFFFu], 1u);
    }
    __syncthreads();
    for (int i = tid; i < 4096; i += 256) {
        u32 c = hist[i];
        if (c) atomicAdd(&a.h24[l * 4096 + i], c);
    }
}

__global__ __launch_bounds__(1024) void k_sel24(SelArgs a) {
    __shared__ u32 h[4096];
    int l = blockIdx.x;
    if (!a.needT[l]) return;
    for (int i = threadIdx.x; i < 4096; i += 1024) h[i] = a.h24[l * 4096 + i];
    __syncthreads();
    if (threadIdx.x == 0) {
        u32 want = a.selst[l * 4 + 1], c = 0;
        for (int b = 4095; b >= 0; --b) {
            c += h[b];
            if (c >= want) {
                a.selst[l * 4 + 2] = (a.selst[l * 4 + 0] << 12) | (u32)b;
                a.selst[l * 4 + 3] = want - (c - h[b]);
                break;
            }
        }
    }
}

__global__ __launch_bounds__(256) void k_h8(SelArgs a) {
    int g = blockIdx.x * 256 + threadIdx.x;
    if (g >= NTOT) return;
    int l, base;
    lvl_lookup(g, l, base);
    if (!a.needT[l]) return;
    u32 key = __float_as_uint(a.sc[l][g - base]);
    if ((key >> 8) == a.selst[l * 4 + 2])
        atomicAdd(&a.h8[l * 256 + (key & 0xFFu)], 1u);
}

__global__ __launch_bounds__(256) void k_sel8(SelArgs a) {
    __shared__ u32 h[256];
    int l = blockIdx.x;
    if (!a.needT[l]) {
        if (threadIdx.x == 0) a.T32[l] = 0u;
        return;
    }
    if (threadIdx.x < 256) h[threadIdx.x] = a.h8[l * 256 + threadIdx.x];
    __syncthreads();
    if (threadIdx.x == 0) {
        u32 want = a.selst[l * 4 + 3], c = 0;
        for (int b = 255; b >= 0; --b) {
            c += h[b];
            if (c >= want) {
                a.T32[l] = (a.selst[l * 4 + 2] << 8) | (u32)b;
                break;
            }
        }
    }
}

__global__ __launch_bounds__(256) void k_compact(SelArgs a) {
    int g = blockIdx.x * 256 + threadIdx.x;
    if (g >= NTOT) return;
    int l, base;
    lvl_lookup(g, l, base);
    int i = g - base;
    u32 key = __float_as_uint(a.sc[l][i]);
    bool pred = (key >= a.T32[l]);
    u64 mask = __ballot(pred);
    int lane = threadIdx.x & 63;
    u32 cnt = (u32)__popcll(mask);
    u32 basep = 0;
    if (cnt) {
        int leader = __ffsll((long long)mask) - 1;
        if (lane == leader) basep = atomicAdd(&a.ccnt[l], cnt);
        basep = __shfl(basep, leader);
    }
    if (pred) {
        u32 off = (u32)__popcll(mask & ((1ull << lane) - 1ull));
        u32 p = basep + off;
        if (p < CAP) a.cand[l * CAP + p] = ((u64)key << 32) | (u32)(~(u32)i);
    }
}

// ============ L2b: sort candidates + decode (verbatim r16) ==================
struct TArgs {
    const u64* cand;
    const u32* ccnt;
    const float* dl[5];
    float* ts[5];
    float* boxes[5];
    float* areas[5];
    int K[5], W[5];
    float stride[5];
    float anc[5][12];
    const float* im_info;
};

__global__ __launch_bounds__(1024) void k_sortdecode(TArgs a) {
    __shared__ u64 sk[CAP];
    int l = blockIdx.x;
    int tid = threadIdx.x;
    u32 cnt = a.ccnt[l];
    if (cnt > CAP) cnt = CAP;
    for (int i = tid; i < CAP; i += 1024)
        sk[i] = (i < (int)cnt) ? a.cand[l * CAP + i] : 0ull;
    __syncthreads();
    for (int k2 = 2; k2 <= CAP; k2 <<= 1)
        for (int j = k2 >> 1; j > 0; j >>= 1) {
            for (int i = tid; i < CAP; i += 1024) {
                int p2 = i ^ j;
                if (p2 > i) {
                    u64 va = sk[i], vb = sk[p2];
                    if ((va < vb) == ((i & k2) == 0)) {
                        sk[i] = vb;
                        sk[p2] = va;
                    }
                }
            }
            __syncthreads();
        }
    int K = a.K[l];
    float imh = a.im_info[0], imw = a.im_info[1];
    float hi_x = __fsub_rn(imw, 1.0f), hi_y = __fsub_rn(imh, 1.0f);
    if (tid < K) {
        u64 v = sk[tid];
        u32 idx = ~(u32)(v & 0xffffffffu);
        float score = __uint_as_float((u32)(v >> 32));
        a.ts[l][tid] = score;
        int aidx = idx % 3;
        int posi = idx / 3;
        int W = a.W[l];
        int rr = posi / W, cc = posi % W;
        float sx = __fmul_rn((float)cc, a.stride[l]);
        float sy = __fmul_rn((float)rr, a.stride[l]);
        const float* an = &a.anc[l][aidx * 4];
        float ax1 = __fadd_rn(an[0], sx), ay1 = __fadd_rn(an[1], sy);
        float ax2 = __fadd_rn(an[2], sx), ay2 = __fadd_rn(an[3], sy);
        float w = __fadd_rn(__fsub_rn(ax2, ax1), 1.0f);
        float h = __fadd_rn(__fsub_rn(ay2, ay1), 1.0f);
        float cx = __fadd_rn(ax1, __fmul_rn(0.5f, w));
        float cy = __fadd_rn(ay1, __fmul_rn(0.5f, h));
        const float* d = &a.dl[l][(size_t)idx * 4];
        float dx = d[0], dy = d[1];
        float dw = fminf(d[2], 4.135166556742356f);
        float dh = fminf(d[3], 4.135166556742356f);
        float pcx = __fadd_rn(__fmul_rn(dx, w), cx);
        float pcy = __fadd_rn(__fmul_rn(dy, h), cy);
        float pw = __fmul_rn(expf(dw), w);
        float ph = __fmul_rn(expf(dh), h);
        float hw2 = __fmul_rn(0.5f, pw), hh2 = __fmul_rn(0.5f, ph);
        float x1 = __fsub_rn(pcx, hw2);
        float y1 = __fsub_rn(pcy, hh2);
        float x2 = __fsub_rn(__fadd_rn(pcx, hw2), 1.0f);
        float y2 = __fsub_rn(__fadd_rn(pcy, hh2), 1.0f);
        x1 = fminf(fmaxf(x1, 0.0f), hi_x);
        y1 = fminf(fmaxf(y1, 0.0f), hi_y);
        x2 = fminf(fmaxf(x2, 0.0f), hi_x);
        y2 = fminf(fmaxf(y2, 0.0f), hi_y);
        float* obx = &a.boxes[l][(size_t)tid * 4];
        obx[0] = x1;
        obx[1] = y1;
        obx[2] = x2;
        obx[3] = y2;
        a.areas[l][tid] = __fmul_rn(__fadd_rn(__fsub_rn(x2, x1), 1.0f),
                                    __fadd_rn(__fsub_rn(y2, y1), 1.0f));
    }
}

// ============ L3a: IoU suppression bit-matrix (verbatim r16) ================
struct IArgs {
    const float* boxes[5];
    const float* areas[5];
    u64* sup[5];
    int K[5];
};

__global__ __launch_bounds__(256) void k_iou(IArgs a) {
    int bx = blockIdx.x;
    int l = bx / 1000;
    int i = bx % 1000;
    int K = a.K[l];
    if (i >= K) return;
    const float* bi = &a.boxes[l][(size_t)i * 4];
    float x1 = bi[0], y1 = bi[1], x2 = bi[2], y2 = bi[3];
    float ai = a.areas[l][i];
    int lane = threadIdx.x & 63;
    int wv = threadIdx.x >> 6;
#pragma unroll
    for (int it = 0; it < 4; ++it) {
        int j = it * 256 + wv * 64 + lane;
        bool sup = false;
        if (j > i && j < K) {
            const float* bj = &a.boxes[l][(size_t)j * 4];
            float xx1 = fmaxf(x1, bj[0]);
            float yy1 = fmaxf(y1, bj[1]);
            float xx2 = fminf(x2, bj[2]);
            float yy2 = fminf(y2, bj[3]);
            float iw = fmaxf(0.0f, __fadd_rn(__fsub_rn(xx2, xx1), 1.0f));
            float ih = fmaxf(0.0f, __fadd_rn(__fsub_rn(yy2, yy1), 1.0f));
            float inter = __fmul_rn(iw, ih);
            float uni = __fsub_rn(__fadd_rn(ai, a.areas[l][j]), inter);
            float iou = __fdiv_rn(inter, uni);
            sup = iou > 0.7f;
        }
        u64 m = __ballot(sup);
        if (lane == 0) a.sup[l][(size_t)i * 16 + it * 4 + wv] = m;
    }
}

// ============ L3b: greedy NMS scan (verbatim r16) ===========================
struct GArgs {
    const u64* sup[5];
    int K[5];
    int* keep[5];
    int* nkeep[5];
};

__global__ __launch_bounds__(64) void k_nms_scan(GArgs a) {
    int l = blockIdx.x;
    int K = a.K[l];
    const u64* __restrict__ sup = a.sup[l];
    int lane = threadIdx.x;
    bool owner = lane < 16;
    u64 mask = 0ull;
    int nk = 0;
    int* keep = a.keep[l];
    u64 r[16];
#pragma unroll
    for (int q = 0; q < 16; ++q)
        r[q] = (owner && q < K) ? sup[(size_t)q * 16 + lane] : 0ull;
    for (int i0 = 0; i0 < K; i0 += 16) {
#pragma unroll
        for (int q = 0; q < 16; ++q) {
            int i = i0 + q;
            if (i < K) {
                u64 w = __shfl(mask, i >> 6);
                bool suppressed = (w >> (i & 63)) & 1ull;
                u64 rowv = r[q];
                int nxt = i + 16;
                r[q] = (owner && nxt < K) ? sup[(size_t)nxt * 16 + lane] : 0ull;
                if (!suppressed) {
                    if (lane == 0) keep[nk] = i;
                    ++nk;
                    mask |= rowv;
                }
            }
        }
    }
    if (lane == 0) *a.nkeep[l] = nk;
}

// ============ L4: emit (verbatim r16) =======================================
struct EArgs {
    const float* ts[5];
    const float* boxes[5];
    const int* keep[5];
    const int* nkeep[5];
    float* ob;
    float* os;
};

__global__ __launch_bounds__(256) void k_emit(EArgs a) {
    int l = blockIdx.x;
    int nk = *a.nkeep[l];
    for (int r = threadIdx.x; r < 1000; r += 256) {
        float b0 = 0, b1 = 0, b2 = 0, b3 = 0, s = -1000000000.0f;
        if (r < nk) {
            int j = a.keep[l][r];
            const float* bp = &a.boxes[l][(size_t)j * 4];
            b0 = bp[0];
            b1 = bp[1];
            b2 = bp[2];
            b3 = bp[3];
            s = a.ts[l][j];
        }
        float* op = &a.ob[(size_t)(l * 1000 + r) * 4];
        op[0] = b0;
        op[1] = b1;
        op[2] = b2;
        op[3] = b3;
        a.os[l * 1000 + r] = s;
    }
}

// ============ L5: final top-1000 (verbatim r16) =============================
__global__ __launch_bounds__(1024) void k_final(const float* __restrict__ ob,
                                                const float* __restrict__ os,
                                                float* __restrict__ out) {
    __shared__ u64 sk[8192];
    int tid = threadIdx.x;
    for (int i = tid; i < 8192; i += 1024)
        sk[i] = (i < 5000) ? (((u64)fkey32(os[i]) << 32) | (u32)(~(u32)i)) : 0ull;
    __syncthreads();
    for (int k2 = 2; k2 <= 8192; k2 <<= 1)
        for (int j = k2 >> 1; j > 0; j >>= 1) {
            for (int i = tid; i < 8192; i += 1024) {
                int p2 = i ^ j;
                if (p2 > i) {
                    u64 va = sk[i], vb = sk[p2];
                    if ((va < vb) == ((i & k2) == 0)) {
                        sk[i] = vb;
                        sk[p2] = va;
                    }
                }
            }
            __syncthreads();
        }
    if (tid < 1000) {
        u64 v = sk[tid];
        u32 gi = ~(u32)(v & 0xffffffffu);
        float s = os[gi];
        const float* b = &ob[(size_t)gi * 4];
        float x1 = b[0], y1 = b[1], x2 = b[2], y2 = b[3];
        out[tid * 4 + 0] = x1;
        out[tid * 4 + 1] = y1;
        out[tid * 4 + 2] = x2;
        out[tid * 4 + 3] = y2;
        out[4000 + tid] = s;
        float area = __fmul_rn(__fadd_rn(__fsub_rn(x2, x1), 1.0f),
                               __fadd_rn(__fsub_rn(y2, y1), 1.0f));
        float scale = __fsqrt_rn(fmaxf(area, 1.0f));
        float t = __fadd_rn(__fdiv_rn(scale, 224.0f), 1e-6f);
        float lv = floorf(__fadd_rn(4.0f, log2f(t)));
        lv = fminf(fmaxf(lv, 2.0f), 5.0f);
        out[5000 + tid] = lv;
    }
}

// ============ host ==========================================================
extern "C" void kernel_launch(void* const* d_in, const int* in_sizes, int n_in,
                              void* d_out, int out_size, void* d_ws, size_t ws_size,
                              hipStream_t stream) {
    const float *fp2 = nullptr, *fp3 = nullptr, *fp4 = nullptr, *fp5 = nullptr, *fp6 = nullptr;
    const float *im_info = nullptr, *conv_w = nullptr, *conv_b = nullptr;
    const float *cls_w = nullptr, *cls_b = nullptr, *bbox_w = nullptr, *bbox_b = nullptr;
    for (int i = 0; i < n_in; ++i) {
        const float* p = (const float*)d_in[i];
        switch (in_sizes[i]) {
            case 16777216: fp2 = p; break;
            case 4194304: fp3 = p; break;
            case 1048576: fp4 = p; break;
            case 262144: fp5 = p; break;
            case 65536: fp6 = p; break;
            case 3: im_info = p; break;
            case 589824: conv_w = p; break;
            case 256: conv_b = p; break;
            case 1536: cls_w = p; break;
            case 6: cls_b = p; break;
            case 3072: bbox_w = p; break;
            case 12: bbox_b = p; break;
            default: break;
        }
    }
    const float* feats[5] = {fp2, fp3, fp4, fp5, fp6};

    size_t off = 0;
    auto take = [&](size_t bytes) -> void* {
        void* p = (char*)d_ws + off;
        off += (bytes + 255) & ~(size_t)255;
        return p;
    };
    double* wT4 = (double*)take((size_t)768 * 256 * 4 * 8);
    int Hs[5] = {256, 128, 64, 32, 16};
    float* scores[5];
    float* deltas[5];
    float* ts[5];
    float* boxes[5];
    float* areas[5];
    int* keep[5];
    int* nkeep[5];
    u64* sup[5];
    int Narr[5], Karr[5];
    for (int s = 0; s < 5; ++s) {
        int H = Hs[s];
        int N = 3 * H * H;
        Narr[s] = N;
        Karr[s] = N < 1000 ? N : 1000;
        scores[s] = (float*)take((size_t)N * 4);
        deltas[s] = (float*)take((size_t)N * 16);
        ts[s] = (float*)take(1024 * 4);
        boxes[s] = (float*)take(1024 * 16);
        areas[s] = (float*)take(1024 * 4);
        keep[s] = (int*)take(1024 * 4);
        nkeep[s] = (int*)take(256);
        sup[s] = (u64*)take((size_t)1000 * 16 * 8);
    }
    float* ob = (float*)take((size_t)5000 * 16);
    float* os = (float*)take((size_t)5000 * 4);
    u32* h12 = (u32*)take(5 * 4096 * 4);
    u32* h24 = (u32*)take(5 * 4096 * 4);
    u32* h8 = (u32*)take(5 * 256 * 4);
    u32* selst = (u32*)take(5 * 4 * 4);
    u32* T32 = (u32*)take(5 * 4);
    u64* cand = (u64*)take((size_t)5 * CAP * 8);
    u32* ccnt = (u32*)take(5 * 4);

    double anc[5][12];
    for (int s = 0; s < 5; ++s) {
        int lvl = 2 + s;
        double stride = (double)(1 << lvl);
        double xc = 0.5 * (stride - 1.0);
        const double ratios[3] = {0.5, 1.0, 2.0};
        for (int rr = 0; rr < 3; ++rr) {
            double wsv = rint(sqrt(stride * stride / ratios[rr]));
            double hsv = rint(wsv * ratios[rr]);
            double WS = wsv * 8.0, HS = hsv * 8.0;
            anc[s][rr * 4 + 0] = xc - 0.5 * (WS - 1.0);
            anc[s][rr * 4 + 1] = xc - 0.5 * (HS - 1.0);
            anc[s][rr * 4 + 2] = xc + 0.5 * (WS - 1.0);
            anc[s][rr * 4 + 3] = xc + 0.5 * (HS - 1.0);
        }
    }

    SelArgs sa;
    TArgs a2;
    IArgs a3;
    GArgs a4;
    EArgs a5;
    for (int s = 0; s < 5; ++s) {
        sa.sc[s] = scores[s];
        sa.N[s] = Narr[s];
        sa.K[s] = Karr[s];
        sa.needT[s] = (Narr[s] > CAP) ? 1 : 0;
        a2.dl[s] = deltas[s];
        a2.ts[s] = ts[s];
        a2.boxes[s] = boxes[s];
        a2.areas[s] = areas[s];
        a2.K[s] = Karr[s];
        a2.W[s] = Hs[s];
        a2.stride[s] = (float)(1 << (2 + s));
        for (int q = 0; q < 12; ++q) a2.anc[s][q] = (float)anc[s][q];
        a3.boxes[s] = boxes[s];
        a3.areas[s] = areas[s];
        a3.sup[s] = sup[s];
        a3.K[s] = Karr[s];
        a4.sup[s] = sup[s];
        a4.K[s] = Karr[s];
        a4.keep[s] = keep[s];
        a4.nkeep[s] = nkeep[s];
        a5.ts[s] = ts[s];
        a5.boxes[s] = boxes[s];
        a5.keep[s] = keep[s];
        a5.nkeep[s] = nkeep[s];
    }
    sa.h12 = h12;
    sa.h24 = h24;
    sa.h8 = h8;
    sa.selst = selst;
    sa.T32 = T32;
    sa.cand = cand;
    sa.ccnt = ccnt;
    a2.cand = cand;
    a2.ccnt = ccnt;
    a2.im_info = im_info;
    a5.ob = ob;
    a5.os = os;

    k_transpose_w<<<dim3(768), dim3(256), 0, stream>>>(conv_w, wT4);
    k_zero<<<dim3((5 * 4096 + 255) / 256), dim3(256), 0, stream>>>(sa);

    CArgs ca;
    for (int s = 0; s < 5; ++s) {
        ca.x[s] = feats[s];
        ca.scores[s] = scores[s];
        ca.deltas[s] = deltas[s];
    }
    ca.wT4 = wT4;
    ca.cb = conv_b;
    ca.clsw = cls_w;
    ca.clsb = cls_b;
    ca.bbw = bbox_w;
    ca.bbb = bbox_b;
    k_conv_heads<<<dim3(5456), dim3(256), 0, stream>>>(ca);

    int fb = (NTOT + 255) / 256;
    k_h12<<<dim3(63), dim3(256), 0, stream>>>(sa);
    k_sel12<<<dim3(5), dim3(1024), 0, stream>>>(sa);
    k_h24<<<dim3(63), dim3(256), 0, stream>>>(sa);
    k_sel24<<<dim3(5), dim3(1024), 0, stream>>>(sa);
    k_h8<<<dim3(fb), dim3(256), 0, stream>>>(sa);
    k_sel8<<<dim3(5), dim3(256), 0, stream>>>(sa);
    k_compact<<<dim3(fb), dim3(256), 0, stream>>>(sa);
    k_sortdecode<<<dim3(5), dim3(1024), 0, stream>>>(a2);
    k_iou<<<dim3(5000), dim3(256), 0, stream>>>(a3);
    k_nms_scan<<<dim3(5), dim3(64), 0, stream>>>(a4);
    k_emit<<<dim3(5), dim3(256), 0, stream>>>(a5);
    k_final<<<dim3(1), dim3(1024), 0, stream>>>(ob, os, (float*)d_out);
}

// Round 18
// 3122.398 us; speedup vs baseline: 1.0239x; 1.0239x over previous
//
#include <hip/hip_runtime.h>
#include <math.h>
#include <stdint.h>

typedef unsigned long long u64;
typedef unsigned int u32;

#define CAP 4096
#define NTOT 261888  // 196608+49152+12288+3072+768

__device__ __forceinline__ u32 fkey32(float f) {
    u32 u = __float_as_uint(f);
    return (u & 0x80000000u) ? ~u : (u | 0x80000000u);
}

// ------- weight transpose -> f32 triplets, 16B padded (3.15MB: L2-resident):
// wt4[((ci*3+dy)*256 + oc)*4 + k] = w[oc][ci][dy*3+k], k=0..2 (k=3 pad)
__global__ __launch_bounds__(256) void k_transpose_w(const float* __restrict__ w,
                                                     float* __restrict__ wt4) {
    int t = blockIdx.x * 256 + threadIdx.x;
    if (t >= 768 * 256) return;
    int r = t >> 8;     // ci*3+dy
    int oc = t & 255;
    float* dst = &wt4[(size_t)t * 4];
    const float* src = &w[(size_t)oc * 2304 + r * 3];
    dst[0] = src[0];
    dst[1] = src[1];
    dst[2] = src[2];
    dst[3] = 0.0f;
}

// ======== L1: fused all-level conv3x3(f64 acc)+relu+heads, 4 blocks/CU ======
// f64 (w,x) fma chain VERBATIM r17 (bit-exact). Weights: one b128 f32 load +
// 3 exact cvts per triplet (2304 cvts/thread ~ 6% of FMA cycles); weight
// array f32 = 3.15MB -> fits per-XCD L2 (r17's 6.29MB f64 thrashed it).
struct CArgs {
    const float* x[5];
    float* scores[5];
    float* deltas[5];
    const float* wt4;
    const float* cb;
    const float* clsw;
    const float* clsb;
    const float* bbw;
    const float* bbb;
};

__global__ __launch_bounds__(256, 4) void k_conv_heads(CArgs ca) {
    __shared__ __align__(16) double xs[64][3][20];  // 30720 B
    __shared__ double hsh[256][4];                  // 8192 B (p-quarter)
    __shared__ float hout[18][16];                  // 1152 B => 40064 B

    int b = blockIdx.x;
    int l, rel;
    if (b < 4096) { l = 0; rel = b; }
    else if (b < 5120) { l = 1; rel = b - 4096; }
    else if (b < 5376) { l = 2; rel = b - 5120; }
    else if (b < 5440) { l = 3; rel = b - 5376; }
    else { l = 4; rel = b - 5440; }
    const int HWs[5] = {256, 128, 64, 32, 16};
    int H = HWs[l], W = H;
    const float* __restrict__ x = ca.x[l];
    float* __restrict__ scores = ca.scores[l];
    float* __restrict__ deltas = ca.deltas[l];
    const float* __restrict__ wt4 = ca.wt4;

    int tid = threadIdx.x;
    int pos0 = rel * 16;
    int row = pos0 / W;
    int col0 = pos0 % W;

    double acc[16];
#pragma unroll
    for (int p = 0; p < 16; ++p) acc[p] = 0.0;

    for (int cc = 0; cc < 4; ++cc) {
        __syncthreads();
        for (int t = tid; t < 64 * 3 * 20; t += 256) {
            int a = t / 60;
            int r = t % 60;
            int dy = r / 20;
            int dxx = r % 20;
            float v = 0.f;
            int gy = row - 1 + dy;
            int gx = col0 - 1 + dxx;
            if (dxx < 18 && gy >= 0 && gy < H && gx >= 0 && gx < W)
                v = x[((size_t)(cc * 64 + a) * H + gy) * W + gx];
            xs[a][dy][dxx] = (double)v;  // exact conversion, once
        }
        __syncthreads();
        int oc = tid;
        for (int a = 0; a < 64; ++a) {
#pragma unroll
            for (int dy = 0; dy < 3; ++dy) {
                double xr[18];
                const double2* xp = (const double2*)&xs[a][dy][0];
#pragma unroll
                for (int q = 0; q < 9; ++q) {
                    double2 v2 = xp[q];
                    xr[2 * q] = v2.x;
                    xr[2 * q + 1] = v2.y;
                }
                int ridx = (cc * 64 + a) * 3 + dy;
                float4 wf = *(const float4*)&wt4[((size_t)ridx * 256 + oc) * 4];
                double w0 = (double)wf.x;
                double w1 = (double)wf.y;
                double w2 = (double)wf.z;
#pragma unroll
                for (int p = 0; p < 16; ++p) {
                    acc[p] = fma(w0, xr[p], acc[p]);
                    acc[p] = fma(w1, xr[p + 1], acc[p]);
                    acc[p] = fma(w2, xr[p + 2], acc[p]);
                }
            }
        }
    }
    // ---- heads in four p-quarter passes (same arithmetic & ci order) ----
    double bias = (double)ca.cb[tid];
    for (int qh = 0; qh < 4; ++qh) {
        __syncthreads();
#pragma unroll
        for (int p = 0; p < 4; ++p) hsh[tid][p] = fmax(acc[qh * 4 + p] + bias, 0.0);
        __syncthreads();
        for (int t = tid; t < 72; t += 256) {
            int p = t & 3, ch = t >> 2;
            double s = (ch < 6) ? (double)ca.clsb[ch] : (double)ca.bbb[ch - 6];
            const float* __restrict__ wv =
                (ch < 6) ? (ca.clsw + ch * 256) : (ca.bbw + (ch - 6) * 256);
            for (int ci = 0; ci < 256; ++ci) s += (double)wv[ci] * hsh[ci][p];
            hout[ch][qh * 4 + p] = (float)s;
        }
    }
    __syncthreads();
    for (int t = tid; t < 48; t += 256) {
        int p = t & 15, a = t >> 4;
        int posi = pos0 + p;
        float c0 = hout[a][p], c1 = hout[3 + a][p];
        float m = fmaxf(c0, c1);
        float e0 = expf(__fsub_rn(c0, m));
        float e1 = expf(__fsub_rn(c1, m));
        scores[(size_t)posi * 3 + a] = __fdiv_rn(e1, __fadd_rn(e0, e1));
    }
    for (int t = tid; t < 192; t += 256) {
        int p = t & 15, j = t >> 4;
        int posi = pos0 + p;
        int a = j >> 2, c = j & 3;
        deltas[((size_t)posi * 3 + a) * 4 + c] = hout[6 + j][p];
    }
}

// ============ top-K selection machinery (verbatim r17) ======================
struct SelArgs {
    const float* sc[5];
    u32* h12;
    u32* h24;
    u32* h8;
    u32* selst;
    u32* T32;
    u64* cand;
    u32* ccnt;
    int N[5], K[5];
    int needT[5];
};

__device__ __forceinline__ void lvl_lookup(int g, int& l, int& base) {
    if (g < 196608) { l = 0; base = 0; }
    else if (g < 245760) { l = 1; base = 196608; }
    else if (g < 258048) { l = 2; base = 245760; }
    else if (g < 261120) { l = 3; base = 258048; }
    else { l = 4; base = 261120; }
}

__device__ __forceinline__ void hblk_lookup(int b, int& l, int& base, int& n0) {
    if (b < 48) { l = 0; base = 0; n0 = b * 4096; }
    else if (b < 60) { l = 1; base = 196608; n0 = (b - 48) * 4096; }
    else { l = 2; base = 245760; n0 = (b - 60) * 4096; }
}

__global__ __launch_bounds__(256) void k_zero(SelArgs a) {
    int g = blockIdx.x * 256 + threadIdx.x;
    if (g < 5 * 4096) { a.h12[g] = 0; a.h24[g] = 0; }
    if (g < 5 * 256) a.h8[g] = 0;
    if (g < 5) a.ccnt[g] = 0;
}

__global__ __launch_bounds__(256) void k_h12(SelArgs a) {
    __shared__ u32 hist[4096];
    int l, base, n0;
    hblk_lookup(blockIdx.x, l, base, n0);
    int tid = threadIdx.x;
    for (int i = tid; i < 4096; i += 256) hist[i] = 0;
    __syncthreads();
    const float* sc = a.sc[l];
    int i0 = n0 + tid;
#pragma unroll
    for (int q = 0; q < 16; ++q) {
        u32 key = __float_as_uint(sc[i0 + q * 256]);
        atomicAdd(&hist[key >> 20], 1u);
    }
    __syncthreads();
    for (int i = tid; i < 4096; i += 256) {
        u32 c = hist[i];
        if (c) atomicAdd(&a.h12[l * 4096 + i], c);
    }
}

__global__ __launch_bounds__(1024) void k_sel12(SelArgs a) {
    __shared__ u32 h[4096];
    int l = blockIdx.x;
    if (!a.needT[l]) return;
    for (int i = threadIdx.x; i < 4096; i += 1024) h[i] = a.h12[l * 4096 + i];
    __syncthreads();
    if (threadIdx.x == 0) {
        u32 K = (u32)a.K[l], c = 0;
        for (int b = 4095; b >= 0; --b) {
            c += h[b];
            if (c >= K) {
                a.selst[l * 4 + 0] = (u32)b;
                a.selst[l * 4 + 1] = K - (c - h[b]);
                break;
            }
        }
    }
}

__global__ __launch_bounds__(256) void k_h24(SelArgs a) {
    __shared__ u32 hist[4096];
    int l, base, n0;
    hblk_lookup(blockIdx.x, l, base, n0);
    int tid = threadIdx.x;
    for (int i = tid; i < 4096; i += 256) hist[i] = 0;
    __syncthreads();
    const float* sc = a.sc[l];
    u32 topbin = a.selst[l * 4 + 0];
    int i0 = n0 + tid;
#pragma unroll
    for (int q = 0; q < 16; ++q) {
        u32 key = __float_as_uint(sc[i0 + q * 256]);
        if ((key >> 20) == topbin) atomicAdd(&hist[(key >> 8) & 0xFFFu], 1u);
    }
    __syncthreads();
    for (int i = tid; i < 4096; i += 256) {
        u32 c = hist[i];
        if (c) atomicAdd(&a.h24[l * 4096 + i], c);
    }
}

__global__ __launch_bounds__(1024) void k_sel24(SelArgs a) {
    __shared__ u32 h[4096];
    int l = blockIdx.x;
    if (!a.needT[l]) return;
    for (int i = threadIdx.x; i < 4096; i += 1024) h[i] = a.h24[l * 4096 + i];
    __syncthreads();
    if (threadIdx.x == 0) {
        u32 want = a.selst[l * 4 + 1], c = 0;
        for (int b = 4095; b >= 0; --b) {
            c += h[b];
            if (c >= want) {
                a.selst[l * 4 + 2] = (a.selst[l * 4 + 0] << 12) | (u32)b;
                a.selst[l * 4 + 3] = want - (c - h[b]);
                break;
            }
        }
    }
}

__global__ __launch_bounds__(256) void k_h8(SelArgs a) {
    int g = blockIdx.x * 256 + threadIdx.x;
    if (g >= NTOT) return;
    int l, base;
    lvl_lookup(g, l, base);
    if (!a.needT[l]) return;
    u32 key = __float_as_uint(a.sc[l][g - base]);
    if ((key >> 8) == a.selst[l * 4 + 2])
        atomicAdd(&a.h8[l * 256 + (key & 0xFFu)], 1u);
}

__global__ __launch_bounds__(256) void k_sel8(SelArgs a) {
    __shared__ u32 h[256];
    int l = blockIdx.x;
    if (!a.needT[l]) {
        if (threadIdx.x == 0) a.T32[l] = 0u;
        return;
    }
    if (threadIdx.x < 256) h[threadIdx.x] = a.h8[l * 256 + threadIdx.x];
    __syncthreads();
    if (threadIdx.x == 0) {
        u32 want = a.selst[l * 4 + 3], c = 0;
        for (int b = 255; b >= 0; --b) {
            c += h[b];
            if (c >= want) {
                a.T32[l] = (a.selst[l * 4 + 2] << 8) | (u32)b;
                break;
            }
        }
    }
}

__global__ __launch_bounds__(256) void k_compact(SelArgs a) {
    int g = blockIdx.x * 256 + threadIdx.x;
    if (g >= NTOT) return;
    int l, base;
    lvl_lookup(g, l, base);
    int i = g - base;
    u32 key = __float_as_uint(a.sc[l][i]);
    bool pred = (key >= a.T32[l]);
    u64 mask = __ballot(pred);
    int lane = threadIdx.x & 63;
    u32 cnt = (u32)__popcll(mask);
    u32 basep = 0;
    if (cnt) {
        int leader = __ffsll((long long)mask) - 1;
        if (lane == leader) basep = atomicAdd(&a.ccnt[l], cnt);
        basep = __shfl(basep, leader);
    }
    if (pred) {
        u32 off = (u32)__popcll(mask & ((1ull << lane) - 1ull));
        u32 p = basep + off;
        if (p < CAP) a.cand[l * CAP + p] = ((u64)key << 32) | (u32)(~(u32)i);
    }
}

// ============ L2b: sort candidates + decode (verbatim r17) ==================
struct TArgs {
    const u64* cand;
    const u32* ccnt;
    const float* dl[5];
    float* ts[5];
    float* boxes[5];
    float* areas[5];
    int K[5], W[5];
    float stride[5];
    float anc[5][12];
    const float* im_info;
};

__global__ __launch_bounds__(1024) void k_sortdecode(TArgs a) {
    __shared__ u64 sk[CAP];
    int l = blockIdx.x;
    int tid = threadIdx.x;
    u32 cnt = a.ccnt[l];
    if (cnt > CAP) cnt = CAP;
    for (int i = tid; i < CAP; i += 1024)
        sk[i] = (i < (int)cnt) ? a.cand[l * CAP + i] : 0ull;
    __syncthreads();
    for (int k2 = 2; k2 <= CAP; k2 <<= 1)
        for (int j = k2 >> 1; j > 0; j >>= 1) {
            for (int i = tid; i < CAP; i += 1024) {
                int p2 = i ^ j;
                if (p2 > i) {
                    u64 va = sk[i], vb = sk[p2];
                    if ((va < vb) == ((i & k2) == 0)) {
                        sk[i] = vb;
                        sk[p2] = va;
                    }
                }
            }
            __syncthreads();
        }
    int K = a.K[l];
    float imh = a.im_info[0], imw = a.im_info[1];
    float hi_x = __fsub_rn(imw, 1.0f), hi_y = __fsub_rn(imh, 1.0f);
    if (tid < K) {
        u64 v = sk[tid];
        u32 idx = ~(u32)(v & 0xffffffffu);
        float score = __uint_as_float((u32)(v >> 32));
        a.ts[l][tid] = score;
        int aidx = idx % 3;
        int posi = idx / 3;
        int W = a.W[l];
        int rr = posi / W, cc = posi % W;
        float sx = __fmul_rn((float)cc, a.stride[l]);
        float sy = __fmul_rn((float)rr, a.stride[l]);
        const float* an = &a.anc[l][aidx * 4];
        float ax1 = __fadd_rn(an[0], sx), ay1 = __fadd_rn(an[1], sy);
        float ax2 = __fadd_rn(an[2], sx), ay2 = __fadd_rn(an[3], sy);
        float w = __fadd_rn(__fsub_rn(ax2, ax1), 1.0f);
        float h = __fadd_rn(__fsub_rn(ay2, ay1), 1.0f);
        float cx = __fadd_rn(ax1, __fmul_rn(0.5f, w));
        float cy = __fadd_rn(ay1, __fmul_rn(0.5f, h));
        const float* d = &a.dl[l][(size_t)idx * 4];
        float dx = d[0], dy = d[1];
        float dw = fminf(d[2], 4.135166556742356f);
        float dh = fminf(d[3], 4.135166556742356f);
        float pcx = __fadd_rn(__fmul_rn(dx, w), cx);
        float pcy = __fadd_rn(__fmul_rn(dy, h), cy);
        float pw = __fmul_rn(expf(dw), w);
        float ph = __fmul_rn(expf(dh), h);
        float hw2 = __fmul_rn(0.5f, pw), hh2 = __fmul_rn(0.5f, ph);
        float x1 = __fsub_rn(pcx, hw2);
        float y1 = __fsub_rn(pcy, hh2);
        float x2 = __fsub_rn(__fadd_rn(pcx, hw2), 1.0f);
        float y2 = __fsub_rn(__fadd_rn(pcy, hh2), 1.0f);
        x1 = fminf(fmaxf(x1, 0.0f), hi_x);
        y1 = fminf(fmaxf(y1, 0.0f), hi_y);
        x2 = fminf(fmaxf(x2, 0.0f), hi_x);
        y2 = fminf(fmaxf(y2, 0.0f), hi_y);
        float* obx = &a.boxes[l][(size_t)tid * 4];
        obx[0] = x1;
        obx[1] = y1;
        obx[2] = x2;
        obx[3] = y2;
        a.areas[l][tid] = __fmul_rn(__fadd_rn(__fsub_rn(x2, x1), 1.0f),
                                    __fadd_rn(__fsub_rn(y2, y1), 1.0f));
    }
}

// ============ L3a: IoU suppression bit-matrix (verbatim r17) ================
struct IArgs {
    const float* boxes[5];
    const float* areas[5];
    u64* sup[5];
    int K[5];
};

__global__ __launch_bounds__(256) void k_iou(IArgs a) {
    int bx = blockIdx.x;
    int l = bx / 1000;
    int i = bx % 1000;
    int K = a.K[l];
    if (i >= K) return;
    const float* bi = &a.boxes[l][(size_t)i * 4];
    float x1 = bi[0], y1 = bi[1], x2 = bi[2], y2 = bi[3];
    float ai = a.areas[l][i];
    int lane = threadIdx.x & 63;
    int wv = threadIdx.x >> 6;
#pragma unroll
    for (int it = 0; it < 4; ++it) {
        int j = it * 256 + wv * 64 + lane;
        bool sup = false;
        if (j > i && j < K) {
            const float* bj = &a.boxes[l][(size_t)j * 4];
            float xx1 = fmaxf(x1, bj[0]);
            float yy1 = fmaxf(y1, bj[1]);
            float xx2 = fminf(x2, bj[2]);
            float yy2 = fminf(y2, bj[3]);
            float iw = fmaxf(0.0f, __fadd_rn(__fsub_rn(xx2, xx1), 1.0f));
            float ih = fmaxf(0.0f, __fadd_rn(__fsub_rn(yy2, yy1), 1.0f));
            float inter = __fmul_rn(iw, ih);
            float uni = __fsub_rn(__fadd_rn(ai, a.areas[l][j]), inter);
            float iou = __fdiv_rn(inter, uni);
            sup = iou > 0.7f;
        }
        u64 m = __ballot(sup);
        if (lane == 0) a.sup[l][(size_t)i * 16 + it * 4 + wv] = m;
    }
}

// ============ L3b: greedy NMS scan (verbatim r17) ===========================
struct GArgs {
    const u64* sup[5];
    int K[5];
    int* keep[5];
    int* nkeep[5];
};

__global__ __launch_bounds__(64) void k_nms_scan(GArgs a) {
    int l = blockIdx.x;
    int K = a.K[l];
    const u64* __restrict__ sup = a.sup[l];
    int lane = threadIdx.x;
    bool owner = lane < 16;
    u64 mask = 0ull;
    int nk = 0;
    int* keep = a.keep[l];
    u64 r[16];
#pragma unroll
    for (int q = 0; q < 16; ++q)
        r[q] = (owner && q < K) ? sup[(size_t)q * 16 + lane] : 0ull;
    for (int i0 = 0; i0 < K; i0 += 16) {
#pragma unroll
        for (int q = 0; q < 16; ++q) {
            int i = i0 + q;
            if (i < K) {
                u64 w = __shfl(mask, i >> 6);
                bool suppressed = (w >> (i & 63)) & 1ull;
                u64 rowv = r[q];
                int nxt = i + 16;
                r[q] = (owner && nxt < K) ? sup[(size_t)nxt * 16 + lane] : 0ull;
                if (!suppressed) {
                    if (lane == 0) keep[nk] = i;
                    ++nk;
                    mask |= rowv;
                }
            }
        }
    }
    if (lane == 0) *a.nkeep[l] = nk;
}

// ============ L4: emit (verbatim r17) =======================================
struct EArgs {
    const float* ts[5];
    const float* boxes[5];
    const int* keep[5];
    const int* nkeep[5];
    float* ob;
    float* os;
};

__global__ __launch_bounds__(256) void k_emit(EArgs a) {
    int l = blockIdx.x;
    int nk = *a.nkeep[l];
    for (int r = threadIdx.x; r < 1000; r += 256) {
        float b0 = 0, b1 = 0, b2 = 0, b3 = 0, s = -1000000000.0f;
        if (r < nk) {
            int j = a.keep[l][r];
            const float* bp = &a.boxes[l][(size_t)j * 4];
            b0 = bp[0];
            b1 = bp[1];
            b2 = bp[2];
            b3 = bp[3];
            s = a.ts[l][j];
        }
        float* op = &a.ob[(size_t)(l * 1000 + r) * 4];
        op[0] = b0;
        op[1] = b1;
        op[2] = b2;
        op[3] = b3;
        a.os[l * 1000 + r] = s;
    }
}

// ============ L5: final top-1000 (verbatim r17) =============================
__global__ __launch_bounds__(1024) void k_final(const float* __restrict__ ob,
                                                const float* __restrict__ os,
                                                float* __restrict__ out) {
    __shared__ u64 sk[8192];
    int tid = threadIdx.x;
    for (int i = tid; i < 8192; i += 1024)
        sk[i] = (i < 5000) ? (((u64)fkey32(os[i]) << 32) | (u32)(~(u32)i)) : 0ull;
    __syncthreads();
    for (int k2 = 2; k2 <= 8192; k2 <<= 1)
        for (int j = k2 >> 1; j > 0; j >>= 1) {
            for (int i = tid; i < 8192; i += 1024) {
                int p2 = i ^ j;
                if (p2 > i) {
                    u64 va = sk[i], vb = sk[p2];
                    if ((va < vb) == ((i & k2) == 0)) {
                        sk[i] = vb;
                        sk[p2] = va;
                    }
                }
            }
            __syncthreads();
        }
    if (tid < 1000) {
        u64 v = sk[tid];
        u32 gi = ~(u32)(v & 0xffffffffu);
        float s = os[gi];
        const float* b = &ob[(size_t)gi * 4];
        float x1 = b[0], y1 = b[1], x2 = b[2], y2 = b[3];
        out[tid * 4 + 0] = x1;
        out[tid * 4 + 1] = y1;
        out[tid * 4 + 2] = x2;
        out[tid * 4 + 3] = y2;
        out[4000 + tid] = s;
        float area = __fmul_rn(__fadd_rn(__fsub_rn(x2, x1), 1.0f),
                               __fadd_rn(__fsub_rn(y2, y1), 1.0f));
        float scale = __fsqrt_rn(fmaxf(area, 1.0f));
        float t = __fadd_rn(__fdiv_rn(scale, 224.0f), 1e-6f);
        float lv = floorf(__fadd_rn(4.0f, log2f(t)));
        lv = fminf(fmaxf(lv, 2.0f), 5.0f);
        out[5000 + tid] = lv;
    }
}

// ============ host ==========================================================
extern "C" void kernel_launch(void* const* d_in, const int* in_sizes, int n_in,
                              void* d_out, int out_size, void* d_ws, size_t ws_size,
                              hipStream_t stream) {
    const float *fp2 = nullptr, *fp3 = nullptr, *fp4 = nullptr, *fp5 = nullptr, *fp6 = nullptr;
    const float *im_info = nullptr, *conv_w = nullptr, *conv_b = nullptr;
    const float *cls_w = nullptr, *cls_b = nullptr, *bbox_w = nullptr, *bbox_b = nullptr;
    for (int i = 0; i < n_in; ++i) {
        const float* p = (const float*)d_in[i];
        switch (in_sizes[i]) {
            case 16777216: fp2 = p; break;
            case 4194304: fp3 = p; break;
            case 1048576: fp4 = p; break;
            case 262144: fp5 = p; break;
            case 65536: fp6 = p; break;
            case 3: im_info = p; break;
            case 589824: conv_w = p; break;
            case 256: conv_b = p; break;
            case 1536: cls_w = p; break;
            case 6: cls_b = p; break;
            case 3072: bbox_w = p; break;
            case 12: bbox_b = p; break;
            default: break;
        }
    }
    const float* feats[5] = {fp2, fp3, fp4, fp5, fp6};

    size_t off = 0;
    auto take = [&](size_t bytes) -> void* {
        void* p = (char*)d_ws + off;
        off += (bytes + 255) & ~(size_t)255;
        return p;
    };
    float* wt4 = (float*)take((size_t)768 * 256 * 4 * 4);
    int Hs[5] = {256, 128, 64, 32, 16};
    float* scores[5];
    float* deltas[5];
    float* ts[5];
    float* boxes[5];
    float* areas[5];
    int* keep[5];
    int* nkeep[5];
    u64* sup[5];
    int Narr[5], Karr[5];
    for (int s = 0; s < 5; ++s) {
        int H = Hs[s];
        int N = 3 * H * H;
        Narr[s] = N;
        Karr[s] = N < 1000 ? N : 1000;
        scores[s] = (float*)take((size_t)N * 4);
        deltas[s] = (float*)take((size_t)N * 16);
        ts[s] = (float*)take(1024 * 4);
        boxes[s] = (float*)take(1024 * 16);
        areas[s] = (float*)take(1024 * 4);
        keep[s] = (int*)take(1024 * 4);
        nkeep[s] = (int*)take(256);
        sup[s] = (u64*)take((size_t)1000 * 16 * 8);
    }
    float* ob = (float*)take((size_t)5000 * 16);
    float* os = (float*)take((size_t)5000 * 4);
    u32* h12 = (u32*)take(5 * 4096 * 4);
    u32* h24 = (u32*)take(5 * 4096 * 4);
    u32* h8 = (u32*)take(5 * 256 * 4);
    u32* selst = (u32*)take(5 * 4 * 4);
    u32* T32 = (u32*)take(5 * 4);
    u64* cand = (u64*)take((size_t)5 * CAP * 8);
    u32* ccnt = (u32*)take(5 * 4);

    double anc[5][12];
    for (int s = 0; s < 5; ++s) {
        int lvl = 2 + s;
        double stride = (double)(1 << lvl);
        double xc = 0.5 * (stride - 1.0);
        const double ratios[3] = {0.5, 1.0, 2.0};
        for (int rr = 0; rr < 3; ++rr) {
            double wsv = rint(sqrt(stride * stride / ratios[rr]));
            double hsv = rint(wsv * ratios[rr]);
            double WS = wsv * 8.0, HS = hsv * 8.0;
            anc[s][rr * 4 + 0] = xc - 0.5 * (WS - 1.0);
            anc[s][rr * 4 + 1] = xc - 0.5 * (HS - 1.0);
            anc[s][rr * 4 + 2] = xc + 0.5 * (WS - 1.0);
            anc[s][rr * 4 + 3] = xc + 0.5 * (HS - 1.0);
        }
    }

    SelArgs sa;
    TArgs a2;
    IArgs a3;
    GArgs a4;
    EArgs a5;
    for (int s = 0; s < 5; ++s) {
        sa.sc[s] = scores[s];
        sa.N[s] = Narr[s];
        sa.K[s] = Karr[s];
        sa.needT[s] = (Narr[s] > CAP) ? 1 : 0;
        a2.dl[s] = deltas[s];
        a2.ts[s] = ts[s];
        a2.boxes[s] = boxes[s];
        a2.areas[s] = areas[s];
        a2.K[s] = Karr[s];
        a2.W[s] = Hs[s];
        a2.stride[s] = (float)(1 << (2 + s));
        for (int q = 0; q < 12; ++q) a2.anc[s][q] = (float)anc[s][q];
        a3.boxes[s] = boxes[s];
        a3.areas[s] = areas[s];
        a3.sup[s] = sup[s];
        a3.K[s] = Karr[s];
        a4.sup[s] = sup[s];
        a4.K[s] = Karr[s];
        a4.keep[s] = keep[s];
        a4.nkeep[s] = nkeep[s];
        a5.ts[s] = ts[s];
        a5.boxes[s] = boxes[s];
        a5.keep[s] = keep[s];
        a5.nkeep[s] = nkeep[s];
    }
    sa.h12 = h12;
    sa.h24 = h24;
    sa.h8 = h8;
    sa.selst = selst;
    sa.T32 = T32;
    sa.cand = cand;
    sa.ccnt = ccnt;
    a2.cand = cand;
    a2.ccnt = ccnt;
    a2.im_info = im_info;
    a5.ob = ob;
    a5.os = os;

    k_transpose_w<<<dim3(768), dim3(256), 0, stream>>>(conv_w, wt4);
    k_zero<<<dim3((5 * 4096 + 255) / 256), dim3(256), 0, stream>>>(sa);

    CArgs ca;
    for (int s = 0; s < 5; ++s) {
        ca.x[s] = feats[s];
        ca.scores[s] = scores[s];
        ca.deltas[s] = deltas[s];
    }
    ca.wt4 = wt4;
    ca.cb = conv_b;
    ca.clsw = cls_w;
    ca.clsb = cls_b;
    ca.bbw = bbox_w;
    ca.bbb = bbox_b;
    k_conv_heads<<<dim3(5456), dim3(256), 0, stream>>>(ca);

    int fb = (NTOT + 255) / 256;
    k_h12<<<dim3(63), dim3(256), 0, stream>>>(sa);
    k_sel12<<<dim3(5), dim3(1024), 0, stream>>>(sa);
    k_h24<<<dim3(63), dim3(256), 0, stream>>>(sa);
    k_sel24<<<dim3(5), dim3(1024), 0, stream>>>(sa);
    k_h8<<<dim3(fb), dim3(256), 0, stream>>>(sa);
    k_sel8<<<dim3(5), dim3(256), 0, stream>>>(sa);
    k_compact<<<dim3(fb), dim3(256), 0, stream>>>(sa);
    k_sortdecode<<<dim3(5), dim3(1024), 0, stream>>>(a2);
    k_iou<<<dim3(5000), dim3(256), 0, stream>>>(a3);
    k_nms_scan<<<dim3(5), dim3(64), 0, stream>>>(a4);
    k_emit<<<dim3(5), dim3(256), 0, stream>>>(a5);
    k_final<<<dim3(1), dim3(1024), 0, stream>>>(ob, os, (float*)d_out);
}

// Round 20
// 3001.457 us; speedup vs baseline: 1.0652x; 1.0403x over previous
//
#include <hip/hip_runtime.h>
#include <math.h>
#include <stdint.h>

typedef unsigned long long u64;
typedef unsigned int u32;

#define CAP 4096
#define NTOT 261888  // 196608+49152+12288+3072+768

__device__ __forceinline__ u32 fkey32(float f) {
    u32 u = __float_as_uint(f);
    return (u & 0x80000000u) ? ~u : (u | 0x80000000u);
}

// ------- weight transpose -> f32 triplets, 16B padded (3.15MB: L2-resident):
// wt4[((ci*3+dy)*256 + oc)*4 + k] = w[oc][ci][dy*3+k], k=0..2 (k=3 pad)
__global__ __launch_bounds__(256) void k_transpose_w(const float* __restrict__ w,
                                                     float* __restrict__ wt4) {
    int t = blockIdx.x * 256 + threadIdx.x;
    if (t >= 768 * 256) return;
    int r = t >> 8;     // ci*3+dy
    int oc = t & 255;
    float* dst = &wt4[(size_t)t * 4];
    const float* src = &w[(size_t)oc * 2304 + r * 3];
    dst[0] = src[0];
    dst[1] = src[1];
    dst[2] = src[2];
    dst[3] = 0.0f;
}

// ======== L1: fused all-level conv3x3(f64 acc)+relu+heads, 4 blocks/CU ======
// f64 (w,x) fma chain — REQUIRED precision (r19 proved f32 conv flips a
// reference decision). Weights f32 triplets (L2-resident), exact cvt in regs.
struct CArgs {
    const float* x[5];
    float* scores[5];
    float* deltas[5];
    const float* wt4;
    const float* cb;
    const float* clsw;
    const float* clsb;
    const float* bbw;
    const float* bbb;
};

__global__ __launch_bounds__(256, 4) void k_conv_heads(CArgs ca) {
    __shared__ __align__(16) double xs[64][3][20];  // 30720 B
    __shared__ double hsh[256][4];                  // 8192 B (p-quarter)
    __shared__ float hout[18][16];                  // 1152 B => 40064 B

    int b = blockIdx.x;
    int l, rel;
    if (b < 4096) { l = 0; rel = b; }
    else if (b < 5120) { l = 1; rel = b - 4096; }
    else if (b < 5376) { l = 2; rel = b - 5120; }
    else if (b < 5440) { l = 3; rel = b - 5376; }
    else { l = 4; rel = b - 5440; }
    const int HWs[5] = {256, 128, 64, 32, 16};
    int H = HWs[l], W = H;
    const float* __restrict__ x = ca.x[l];
    float* __restrict__ scores = ca.scores[l];
    float* __restrict__ deltas = ca.deltas[l];
    const float* __restrict__ wt4 = ca.wt4;

    int tid = threadIdx.x;
    int pos0 = rel * 16;
    int row = pos0 / W;
    int col0 = pos0 % W;

    double acc[16];
#pragma unroll
    for (int p = 0; p < 16; ++p) acc[p] = 0.0;

    for (int cc = 0; cc < 4; ++cc) {
        __syncthreads();
        for (int t = tid; t < 64 * 3 * 20; t += 256) {
            int a = t / 60;
            int r = t % 60;
            int dy = r / 20;
            int dxx = r % 20;
            float v = 0.f;
            int gy = row - 1 + dy;
            int gx = col0 - 1 + dxx;
            if (dxx < 18 && gy >= 0 && gy < H && gx >= 0 && gx < W)
                v = x[((size_t)(cc * 64 + a) * H + gy) * W + gx];
            xs[a][dy][dxx] = (double)v;  // exact conversion, once
        }
        __syncthreads();
        int oc = tid;
        for (int a = 0; a < 64; ++a) {
#pragma unroll
            for (int dy = 0; dy < 3; ++dy) {
                double xr[18];
                const double2* xp = (const double2*)&xs[a][dy][0];
#pragma unroll
                for (int q = 0; q < 9; ++q) {
                    double2 v2 = xp[q];
                    xr[2 * q] = v2.x;
                    xr[2 * q + 1] = v2.y;
                }
                int ridx = (cc * 64 + a) * 3 + dy;
                float4 wf = *(const float4*)&wt4[((size_t)ridx * 256 + oc) * 4];
                double w0 = (double)wf.x;
                double w1 = (double)wf.y;
                double w2 = (double)wf.z;
#pragma unroll
                for (int p = 0; p < 16; ++p) {
                    acc[p] = fma(w0, xr[p], acc[p]);
                    acc[p] = fma(w1, xr[p + 1], acc[p]);
                    acc[p] = fma(w2, xr[p + 2], acc[p]);
                }
            }
        }
    }
    // ---- heads in four p-quarter passes (same arithmetic & ci order) ----
    double bias = (double)ca.cb[tid];
    for (int qh = 0; qh < 4; ++qh) {
        __syncthreads();
#pragma unroll
        for (int p = 0; p < 4; ++p) hsh[tid][p] = fmax(acc[qh * 4 + p] + bias, 0.0);
        __syncthreads();
        for (int t = tid; t < 72; t += 256) {
            int p = t & 3, ch = t >> 2;
            double s = (ch < 6) ? (double)ca.clsb[ch] : (double)ca.bbb[ch - 6];
            const float* __restrict__ wv =
                (ch < 6) ? (ca.clsw + ch * 256) : (ca.bbw + (ch - 6) * 256);
            for (int ci = 0; ci < 256; ++ci) s += (double)wv[ci] * hsh[ci][p];
            hout[ch][qh * 4 + p] = (float)s;
        }
    }
    __syncthreads();
    for (int t = tid; t < 48; t += 256) {
        int p = t & 15, a = t >> 4;
        int posi = pos0 + p;
        float c0 = hout[a][p], c1 = hout[3 + a][p];
        float m = fmaxf(c0, c1);
        float e0 = expf(__fsub_rn(c0, m));
        float e1 = expf(__fsub_rn(c1, m));
        scores[(size_t)posi * 3 + a] = __fdiv_rn(e1, __fadd_rn(e0, e1));
    }
    for (int t = tid; t < 192; t += 256) {
        int p = t & 15, j = t >> 4;
        int posi = pos0 + p;
        int a = j >> 2, c = j & 3;
        deltas[((size_t)posi * 3 + a) * 4 + c] = hout[6 + j][p];
    }
}

// ============ top-K selection machinery (verbatim r18) ======================
struct SelArgs {
    const float* sc[5];
    u32* h12;
    u32* h24;
    u32* h8;
    u32* selst;
    u32* T32;
    u64* cand;
    u32* ccnt;
    int N[5], K[5];
    int needT[5];
};

__device__ __forceinline__ void lvl_lookup(int g, int& l, int& base) {
    if (g < 196608) { l = 0; base = 0; }
    else if (g < 245760) { l = 1; base = 196608; }
    else if (g < 258048) { l = 2; base = 245760; }
    else if (g < 261120) { l = 3; base = 258048; }
    else { l = 4; base = 261120; }
}

__device__ __forceinline__ void hblk_lookup(int b, int& l, int& base, int& n0) {
    if (b < 48) { l = 0; base = 0; n0 = b * 4096; }
    else if (b < 60) { l = 1; base = 196608; n0 = (b - 48) * 4096; }
    else { l = 2; base = 245760; n0 = (b - 60) * 4096; }
}

__global__ __launch_bounds__(256) void k_zero(SelArgs a) {
    int g = blockIdx.x * 256 + threadIdx.x;
    if (g < 5 * 4096) { a.h12[g] = 0; a.h24[g] = 0; }
    if (g < 5 * 256) a.h8[g] = 0;
    if (g < 5) a.ccnt[g] = 0;
}

__global__ __launch_bounds__(256) void k_h12(SelArgs a) {
    __shared__ u32 hist[4096];
    int l, base, n0;
    hblk_lookup(blockIdx.x, l, base, n0);
    int tid = threadIdx.x;
    for (int i = tid; i < 4096; i += 256) hist[i] = 0;
    __syncthreads();
    const float* sc = a.sc[l];
    int i0 = n0 + tid;
#pragma unroll
    for (int q = 0; q < 16; ++q) {
        u32 key = __float_as_uint(sc[i0 + q * 256]);
        atomicAdd(&hist[key >> 20], 1u);
    }
    __syncthreads();
    for (int i = tid; i < 4096; i += 256) {
        u32 c = hist[i];
        if (c) atomicAdd(&a.h12[l * 4096 + i], c);
    }
}

__global__ __launch_bounds__(1024) void k_sel12(SelArgs a) {
    __shared__ u32 h[4096];
    int l = blockIdx.x;
    if (!a.needT[l]) return;
    for (int i = threadIdx.x; i < 4096; i += 1024) h[i] = a.h12[l * 4096 + i];
    __syncthreads();
    if (threadIdx.x == 0) {
        u32 K = (u32)a.K[l], c = 0;
        for (int b = 4095; b >= 0; --b) {
            c += h[b];
            if (c >= K) {
                a.selst[l * 4 + 0] = (u32)b;
                a.selst[l * 4 + 1] = K - (c - h[b]);
                break;
            }
        }
    }
}

__global__ __launch_bounds__(256) void k_h24(SelArgs a) {
    __shared__ u32 hist[4096];
    int l, base, n0;
    hblk_lookup(blockIdx.x, l, base, n0);
    int tid = threadIdx.x;
    for (int i = tid; i < 4096; i += 256) hist[i] = 0;
    __syncthreads();
    const float* sc = a.sc[l];
    u32 topbin = a.selst[l * 4 + 0];
    int i0 = n0 + tid;
#pragma unroll
    for (int q = 0; q < 16; ++q) {
        u32 key = __float_as_uint(sc[i0 + q * 256]);
        if ((key >> 20) == topbin) atomicAdd(&hist[(key >> 8) & 0xFFFu], 1u);
    }
    __syncthreads();
    for (int i = tid; i < 4096; i += 256) {
        u32 c = hist[i];
        if (c) atomicAdd(&a.h24[l * 4096 + i], c);
    }
}

__global__ __launch_bounds__(1024) void k_sel24(SelArgs a) {
    __shared__ u32 h[4096];
    int l = blockIdx.x;
    if (!a.needT[l]) return;
    for (int i = threadIdx.x; i < 4096; i += 1024) h[i] = a.h24[l * 4096 + i];
    __syncthreads();
    if (threadIdx.x == 0) {
        u32 want = a.selst[l * 4 + 1], c = 0;
        for (int b = 4095; b >= 0; --b) {
            c += h[b];
            if (c >= want) {
                a.selst[l * 4 + 2] = (a.selst[l * 4 + 0] << 12) | (u32)b;
                a.selst[l * 4 + 3] = want - (c - h[b]);
                break;
            }
        }
    }
}

__global__ __launch_bounds__(256) void k_h8(SelArgs a) {
    int g = blockIdx.x * 256 + threadIdx.x;
    if (g >= NTOT) return;
    int l, base;
    lvl_lookup(g, l, base);
    if (!a.needT[l]) return;
    u32 key = __float_as_uint(a.sc[l][g - base]);
    if ((key >> 8) == a.selst[l * 4 + 2])
        atomicAdd(&a.h8[l * 256 + (key & 0xFFu)], 1u);
}

__global__ __launch_bounds__(256) void k_sel8(SelArgs a) {
    __shared__ u32 h[256];
    int l = blockIdx.x;
    if (!a.needT[l]) {
        if (threadIdx.x == 0) a.T32[l] = 0u;
        return;
    }
    if (threadIdx.x < 256) h[threadIdx.x] = a.h8[l * 256 + threadIdx.x];
    __syncthreads();
    if (threadIdx.x == 0) {
        u32 want = a.selst[l * 4 + 3], c = 0;
        for (int b = 255; b >= 0; --b) {
            c += h[b];
            if (c >= want) {
                a.T32[l] = (a.selst[l * 4 + 2] << 8) | (u32)b;
                break;
            }
        }
    }
}

__global__ __launch_bounds__(256) void k_compact(SelArgs a) {
    int g = blockIdx.x * 256 + threadIdx.x;
    if (g >= NTOT) return;
    int l, base;
    lvl_lookup(g, l, base);
    int i = g - base;
    u32 key = __float_as_uint(a.sc[l][i]);
    bool pred = (key >= a.T32[l]);
    u64 mask = __ballot(pred);
    int lane = threadIdx.x & 63;
    u32 cnt = (u32)__popcll(mask);
    u32 basep = 0;
    if (cnt) {
        int leader = __ffsll((long long)mask) - 1;
        if (lane == leader) basep = atomicAdd(&a.ccnt[l], cnt);
        basep = __shfl(basep, leader);
    }
    if (pred) {
        u32 off = (u32)__popcll(mask & ((1ull << lane) - 1ull));
        u32 p = basep + off;
        if (p < CAP) a.cand[l * CAP + p] = ((u64)key << 32) | (u32)(~(u32)i);
    }
}

// ============ L2b: sort candidates + decode (verbatim r18) ==================
struct TArgs {
    const u64* cand;
    const u32* ccnt;
    const float* dl[5];
    float* ts[5];
    float* boxes[5];
    float* areas[5];
    int K[5], W[5];
    float stride[5];
    float anc[5][12];
    const float* im_info;
};

__global__ __launch_bounds__(1024) void k_sortdecode(TArgs a) {
    __shared__ u64 sk[CAP];
    int l = blockIdx.x;
    int tid = threadIdx.x;
    u32 cnt = a.ccnt[l];
    if (cnt > CAP) cnt = CAP;
    for (int i = tid; i < CAP; i += 1024)
        sk[i] = (i < (int)cnt) ? a.cand[l * CAP + i] : 0ull;
    __syncthreads();
    for (int k2 = 2; k2 <= CAP; k2 <<= 1)
        for (int j = k2 >> 1; j > 0; j >>= 1) {
            for (int i = tid; i < CAP; i += 1024) {
                int p2 = i ^ j;
                if (p2 > i) {
                    u64 va = sk[i], vb = sk[p2];
                    if ((va < vb) == ((i & k2) == 0)) {
                        sk[i] = vb;
                        sk[p2] = va;
                    }
                }
            }
            __syncthreads();
        }
    int K = a.K[l];
    float imh = a.im_info[0], imw = a.im_info[1];
    float hi_x = __fsub_rn(imw, 1.0f), hi_y = __fsub_rn(imh, 1.0f);
    if (tid < K) {
        u64 v = sk[tid];
        u32 idx = ~(u32)(v & 0xffffffffu);
        float score = __uint_as_float((u32)(v >> 32));
        a.ts[l][tid] = score;
        int aidx = idx % 3;
        int posi = idx / 3;
        int W = a.W[l];
        int rr = posi / W, cc = posi % W;
        float sx = __fmul_rn((float)cc, a.stride[l]);
        float sy = __fmul_rn((float)rr, a.stride[l]);
        const float* an = &a.anc[l][aidx * 4];
        float ax1 = __fadd_rn(an[0], sx), ay1 = __fadd_rn(an[1], sy);
        float ax2 = __fadd_rn(an[2], sx), ay2 = __fadd_rn(an[3], sy);
        float w = __fadd_rn(__fsub_rn(ax2, ax1), 1.0f);
        float h = __fadd_rn(__fsub_rn(ay2, ay1), 1.0f);
        float cx = __fadd_rn(ax1, __fmul_rn(0.5f, w));
        float cy = __fadd_rn(ay1, __fmul_rn(0.5f, h));
        const float* d = &a.dl[l][(size_t)idx * 4];
        float dx = d[0], dy = d[1];
        float dw = fminf(d[2], 4.135166556742356f);
        float dh = fminf(d[3], 4.135166556742356f);
        float pcx = __fadd_rn(__fmul_rn(dx, w), cx);
        float pcy = __fadd_rn(__fmul_rn(dy, h), cy);
        float pw = __fmul_rn(expf(dw), w);
        float ph = __fmul_rn(expf(dh), h);
        float hw2 = __fmul_rn(0.5f, pw), hh2 = __fmul_rn(0.5f, ph);
        float x1 = __fsub_rn(pcx, hw2);
        float y1 = __fsub_rn(pcy, hh2);
        float x2 = __fsub_rn(__fadd_rn(pcx, hw2), 1.0f);
        float y2 = __fsub_rn(__fadd_rn(pcy, hh2), 1.0f);
        x1 = fminf(fmaxf(x1, 0.0f), hi_x);
        y1 = fminf(fmaxf(y1, 0.0f), hi_y);
        x2 = fminf(fmaxf(x2, 0.0f), hi_x);
        y2 = fminf(fmaxf(y2, 0.0f), hi_y);
        float* obx = &a.boxes[l][(size_t)tid * 4];
        obx[0] = x1;
        obx[1] = y1;
        obx[2] = x2;
        obx[3] = y2;
        a.areas[l][tid] = __fmul_rn(__fadd_rn(__fsub_rn(x2, x1), 1.0f),
                                    __fadd_rn(__fsub_rn(y2, y1), 1.0f));
    }
}

// ============ L3a: IoU suppression bit-matrix (verbatim r18) ================
struct IArgs {
    const float* boxes[5];
    const float* areas[5];
    u64* sup[5];
    int K[5];
};

__global__ __launch_bounds__(256) void k_iou(IArgs a) {
    int bx = blockIdx.x;
    int l = bx / 1000;
    int i = bx % 1000;
    int K = a.K[l];
    if (i >= K) return;
    const float* bi = &a.boxes[l][(size_t)i * 4];
    float x1 = bi[0], y1 = bi[1], x2 = bi[2], y2 = bi[3];
    float ai = a.areas[l][i];
    int lane = threadIdx.x & 63;
    int wv = threadIdx.x >> 6;
#pragma unroll
    for (int it = 0; it < 4; ++it) {
        int j = it * 256 + wv * 64 + lane;
        bool sup = false;
        if (j > i && j < K) {
            const float* bj = &a.boxes[l][(size_t)j * 4];
            float xx1 = fmaxf(x1, bj[0]);
            float yy1 = fmaxf(y1, bj[1]);
            float xx2 = fminf(x2, bj[2]);
            float yy2 = fminf(y2, bj[3]);
            float iw = fmaxf(0.0f, __fadd_rn(__fsub_rn(xx2, xx1), 1.0f));
            float ih = fmaxf(0.0f, __fadd_rn(__fsub_rn(yy2, yy1), 1.0f));
            float inter = __fmul_rn(iw, ih);
            float uni = __fsub_rn(__fadd_rn(ai, a.areas[l][j]), inter);
            float iou = __fdiv_rn(inter, uni);
            sup = iou > 0.7f;
        }
        u64 m = __ballot(sup);
        if (lane == 0) a.sup[l][(size_t)i * 16 + it * 4 + wv] = m;
    }
}

// ============ L3b: greedy NMS scan (verbatim r18) ===========================
struct GArgs {
    const u64* sup[5];
    int K[5];
    int* keep[5];
    int* nkeep[5];
};

__global__ __launch_bounds__(64) void k_nms_scan(GArgs a) {
    int l = blockIdx.x;
    int K = a.K[l];
    const u64* __restrict__ sup = a.sup[l];
    int lane = threadIdx.x;
    bool owner = lane < 16;
    u64 mask = 0ull;
    int nk = 0;
    int* keep = a.keep[l];
    u64 r[16];
#pragma unroll
    for (int q = 0; q < 16; ++q)
        r[q] = (owner && q < K) ? sup[(size_t)q * 16 + lane] : 0ull;
    for (int i0 = 0; i0 < K; i0 += 16) {
#pragma unroll
        for (int q = 0; q < 16; ++q) {
            int i = i0 + q;
            if (i < K) {
                u64 w = __shfl(mask, i >> 6);
                bool suppressed = (w >> (i & 63)) & 1ull;
                u64 rowv = r[q];
                int nxt = i + 16;
                r[q] = (owner && nxt < K) ? sup[(size_t)nxt * 16 + lane] : 0ull;
                if (!suppressed) {
                    if (lane == 0) keep[nk] = i;
                    ++nk;
                    mask |= rowv;
                }
            }
        }
    }
    if (lane == 0) *a.nkeep[l] = nk;
}

// ============ L4: emit (verbatim r18) =======================================
struct EArgs {
    const float* ts[5];
    const float* boxes[5];
    const int* keep[5];
    const int* nkeep[5];
    float* ob;
    float* os;
};

__global__ __launch_bounds__(256) void k_emit(EArgs a) {
    int l = blockIdx.x;
    int nk = *a.nkeep[l];
    for (int r = threadIdx.x; r < 1000; r += 256) {
        float b0 = 0, b1 = 0, b2 = 0, b3 = 0, s = -1000000000.0f;
        if (r < nk) {
            int j = a.keep[l][r];
            const float* bp = &a.boxes[l][(size_t)j * 4];
            b0 = bp[0];
            b1 = bp[1];
            b2 = bp[2];
            b3 = bp[3];
            s = a.ts[l][j];
        }
        float* op = &a.ob[(size_t)(l * 1000 + r) * 4];
        op[0] = b0;
        op[1] = b1;
        op[2] = b2;
        op[3] = b3;
        a.os[l * 1000 + r] = s;
    }
}

// ============ L5: final top-1000 (verbatim r18) =============================
__global__ __launch_bounds__(1024) void k_final(const float* __restrict__ ob,
                                                const float* __restrict__ os,
                                                float* __restrict__ out) {
    __shared__ u64 sk[8192];
    int tid = threadIdx.x;
    for (int i = tid; i < 8192; i += 1024)
        sk[i] = (i < 5000) ? (((u64)fkey32(os[i]) << 32) | (u32)(~(u32)i)) : 0ull;
    __syncthreads();
    for (int k2 = 2; k2 <= 8192; k2 <<= 1)
        for (int j = k2 >> 1; j > 0; j >>= 1) {
            for (int i = tid; i < 8192; i += 1024) {
                int p2 = i ^ j;
                if (p2 > i) {
                    u64 va = sk[i], vb = sk[p2];
                    if ((va < vb) == ((i & k2) == 0)) {
                        sk[i] = vb;
                        sk[p2] = va;
                    }
                }
            }
            __syncthreads();
        }
    if (tid < 1000) {
        u64 v = sk[tid];
        u32 gi = ~(u32)(v & 0xffffffffu);
        float s = os[gi];
        const float* b = &ob[(size_t)gi * 4];
        float x1 = b[0], y1 = b[1], x2 = b[2], y2 = b[3];
        out[tid * 4 + 0] = x1;
        out[tid * 4 + 1] = y1;
        out[tid * 4 + 2] = x2;
        out[tid * 4 + 3] = y2;
        out[4000 + tid] = s;
        float area = __fmul_rn(__fadd_rn(__fsub_rn(x2, x1), 1.0f),
                               __fadd_rn(__fsub_rn(y2, y1), 1.0f));
        float scale = __fsqrt_rn(fmaxf(area, 1.0f));
        float t = __fadd_rn(__fdiv_rn(scale, 224.0f), 1e-6f);
        float lv = floorf(__fadd_rn(4.0f, log2f(t)));
        lv = fminf(fmaxf(lv, 2.0f), 5.0f);
        out[5000 + tid] = lv;
    }
}

// ============ host ==========================================================
extern "C" void kernel_launch(void* const* d_in, const int* in_sizes, int n_in,
                              void* d_out, int out_size, void* d_ws, size_t ws_size,
                              hipStream_t stream) {
    const float *fp2 = nullptr, *fp3 = nullptr, *fp4 = nullptr, *fp5 = nullptr, *fp6 = nullptr;
    const float *im_info = nullptr, *conv_w = nullptr, *conv_b = nullptr;
    const float *cls_w = nullptr, *cls_b = nullptr, *bbox_w = nullptr, *bbox_b = nullptr;
    for (int i = 0; i < n_in; ++i) {
        const float* p = (const float*)d_in[i];
        switch (in_sizes[i]) {
            case 16777216: fp2 = p; break;
            case 4194304: fp3 = p; break;
            case 1048576: fp4 = p; break;
            case 262144: fp5 = p; break;
            case 65536: fp6 = p; break;
            case 3: im_info = p; break;
            case 589824: conv_w = p; break;
            case 256: conv_b = p; break;
            case 1536: cls_w = p; break;
            case 6: cls_b = p; break;
            case 3072: bbox_w = p; break;
            case 12: bbox_b = p; break;
            default: break;
        }
    }
    const float* feats[5] = {fp2, fp3, fp4, fp5, fp6};

    size_t off = 0;
    auto take = [&](size_t bytes) -> void* {
        void* p = (char*)d_ws + off;
        off += (bytes + 255) & ~(size_t)255;
        return p;
    };
    float* wt4 = (float*)take((size_t)768 * 256 * 4 * 4);
    int Hs[5] = {256, 128, 64, 32, 16};
    float* scores[5];
    float* deltas[5];
    float* ts[5];
    float* boxes[5];
    float* areas[5];
    int* keep[5];
    int* nkeep[5];
    u64* sup[5];
    int Narr[5], Karr[5];
    for (int s = 0; s < 5; ++s) {
        int H = Hs[s];
        int N = 3 * H * H;
        Narr[s] = N;
        Karr[s] = N < 1000 ? N : 1000;
        scores[s] = (float*)take((size_t)N * 4);
        deltas[s] = (float*)take((size_t)N * 16);
        ts[s] = (float*)take(1024 * 4);
        boxes[s] = (float*)take(1024 * 16);
        areas[s] = (float*)take(1024 * 4);
        keep[s] = (int*)take(1024 * 4);
        nkeep[s] = (int*)take(256);
        sup[s] = (u64*)take((size_t)1000 * 16 * 8);
    }
    float* ob = (float*)take((size_t)5000 * 16);
    float* os = (float*)take((size_t)5000 * 4);
    u32* h12 = (u32*)take(5 * 4096 * 4);
    u32* h24 = (u32*)take(5 * 4096 * 4);
    u32* h8 = (u32*)take(5 * 256 * 4);
    u32* selst = (u32*)take(5 * 4 * 4);
    u32* T32 = (u32*)take(5 * 4);
    u64* cand = (u64*)take((size_t)5 * CAP * 8);
    u32* ccnt = (u32*)take(5 * 4);

    double anc[5][12];
    for (int s = 0; s < 5; ++s) {
        int lvl = 2 + s;
        double stride = (double)(1 << lvl);
        double xc = 0.5 * (stride - 1.0);
        const double ratios[3] = {0.5, 1.0, 2.0};
        for (int rr = 0; rr < 3; ++rr) {
            double wsv = rint(sqrt(stride * stride / ratios[rr]));
            double hsv = rint(wsv * ratios[rr]);
            double WS = wsv * 8.0, HS = hsv * 8.0;
            anc[s][rr * 4 + 0] = xc - 0.5 * (WS - 1.0);
            anc[s][rr * 4 + 1] = xc - 0.5 * (HS - 1.0);
            anc[s][rr * 4 + 2] = xc + 0.5 * (WS - 1.0);
            anc[s][rr * 4 + 3] = xc + 0.5 * (HS - 1.0);
        }
    }

    SelArgs sa;
    TArgs a2;
    IArgs a3;
    GArgs a4;
    EArgs a5;
    for (int s = 0; s < 5; ++s) {
        sa.sc[s] = scores[s];
        sa.N[s] = Narr[s];
        sa.K[s] = Karr[s];
        sa.needT[s] = (Narr[s] > CAP) ? 1 : 0;
        a2.dl[s] = deltas[s];
        a2.ts[s] = ts[s];
        a2.boxes[s] = boxes[s];
        a2.areas[s] = areas[s];
        a2.K[s] = Karr[s];
        a2.W[s] = Hs[s];
        a2.stride[s] = (float)(1 << (2 + s));
        for (int q = 0; q < 12; ++q) a2.anc[s][q] = (float)anc[s][q];
        a3.boxes[s] = boxes[s];
        a3.areas[s] = areas[s];
        a3.sup[s] = sup[s];
        a3.K[s] = Karr[s];
        a4.sup[s] = sup[s];
        a4.K[s] = Karr[s];
        a4.keep[s] = keep[s];
        a4.nkeep[s] = nkeep[s];
        a5.ts[s] = ts[s];
        a5.boxes[s] = boxes[s];
        a5.keep[s] = keep[s];
        a5.nkeep[s] = nkeep[s];
    }
    sa.h12 = h12;
    sa.h24 = h24;
    sa.h8 = h8;
    sa.selst = selst;
    sa.T32 = T32;
    sa.cand = cand;
    sa.ccnt = ccnt;
    a2.cand = cand;
    a2.ccnt = ccnt;
    a2.im_info = im_info;
    a5.ob = ob;
    a5.os = os;

    k_transpose_w<<<dim3(768), dim3(256), 0, stream>>>(conv_w, wt4);
    k_zero<<<dim3((5 * 4096 + 255) / 256), dim3(256), 0, stream>>>(sa);

    CArgs ca;
    for (int s = 0; s < 5; ++s) {
        ca.x[s] = feats[s];
        ca.scores[s] = scores[s];
        ca.deltas[s] = deltas[s];
    }
    ca.wt4 = wt4;
    ca.cb = conv_b;
    ca.clsw = cls_w;
    ca.clsb = cls_b;
    ca.bbw = bbox_w;
    ca.bbb = bbox_b;
    k_conv_heads<<<dim3(5456), dim3(256), 0, stream>>>(ca);

    int fb = (NTOT + 255) / 256;
    k_h12<<<dim3(63), dim3(256), 0, stream>>>(sa);
    k_sel12<<<dim3(5), dim3(1024), 0, stream>>>(sa);
    k_h24<<<dim3(63), dim3(256), 0, stream>>>(sa);
    k_sel24<<<dim3(5), dim3(1024), 0, stream>>>(sa);
    k_h8<<<dim3(fb), dim3(256), 0, stream>>>(sa);
    k_sel8<<<dim3(5), dim3(256), 0, stream>>>(sa);
    k_compact<<<dim3(fb), dim3(256), 0, stream>>>(sa);
    k_sortdecode<<<dim3(5), dim3(1024), 0, stream>>>(a2);
    k_iou<<<dim3(5000), dim3(256), 0, stream>>>(a3);
    k_nms_scan<<<dim3(5), dim3(64), 0, stream>>>(a4);
    k_emit<<<dim3(5), dim3(256), 0, stream>>>(a5);
    k_final<<<dim3(1), dim3(1024), 0, stream>>>(ob, os, (float*)d_out);
}